// Round 3
// baseline (224.026 us; speedup 1.0000x reference)
//
#include <hip/hip_runtime.h>
#include <hip/hip_bf16.h>

// CausalAttentionModule: B=4, C=64, H=W=64, NH=8, hd=8, BL=5, BS=25, MASK_ONES=12
// Key algebra:
//   - unfold rows are gathers of neighbor pixels -> LN1+QKV computed once per pixel
//   - masked / OOB rows -> constant qkv row (qkv_const)
//   - sum over q of attn@v -> column sums w[k]; k>=12 collapses to scalar wc
//   - exp(dot+bias) = exp(dot)*exp(bias), exp(bias) precomputed per launch

typedef _Float16 h2f __attribute__((ext_vector_type(2)));

__device__ __forceinline__ float fdot2f(h2f a, h2f b, float c) {
#if defined(__has_builtin)
#if __has_builtin(__builtin_amdgcn_fdot2)
    return __builtin_amdgcn_fdot2(a, b, c, false);
#else
    return c + (float)a.x * (float)b.x + (float)a.y * (float)b.y;
#endif
#else
    return c + (float)a.x * (float)b.x + (float)a.y * (float)b.y;
#endif
}

__device__ __forceinline__ float frcp(float x) {
#if defined(__has_builtin)
#if __has_builtin(__builtin_amdgcn_rcpf)
    return __builtin_amdgcn_rcpf(x);
#else
    return 1.0f / x;
#endif
#else
    return 1.0f / x;
#endif
}

#define SC 0.35355339059327373f  // 1/sqrt(8)

// ---------------- K1: LN1 + QKV (plus setup block) ----------------
__global__ __launch_bounds__(256) void k_qkv(
    const float* __restrict__ x, const float* __restrict__ n1w, const float* __restrict__ n1b,
    const float* __restrict__ qw, const float* __restrict__ qb, const float* __restrict__ rpb,
    float* __restrict__ qkv_all, float* __restrict__ qkvc,
    float* __restrict__ eb, float* __restrict__ ebs)
{
    const int t = threadIdx.x;
    if (blockIdx.x == 256) {
        // qkv_const = LN(0) @ qkv_w^T + qkv_b = n1b @ qkv_w^T + qkv_b
        if (t < 192) {
            float acc = qb[t];
            for (int c = 0; c < 64; ++c) acc += n1b[c] * qw[t * 64 + c];
            qkvc[t] = acc;
        }
        // exp(bias) table, k<12 only: eb[h][q][k] (stride 12)
        for (int i = t; i < 2400; i += 256) {
            int h = i / 300, r = i % 300, q = r / 12, k = r % 12;
            int idx = (q / 5 - k / 5 + 4) * 9 + (q % 5 - k % 5 + 4);
            eb[i] = __expf(rpb[idx * 8 + h]);
        }
        // row sums over k=12..24: ebs[h][q]
        for (int i = t; i < 200; i += 256) {
            int h = i / 25, q = i % 25;
            float s = 0.f;
            for (int k = 12; k < 25; ++k) {
                int idx = (q / 5 - k / 5 + 4) * 9 + (q % 5 - k % 5 + 4);
                s += __expf(rpb[idx * 8 + h]);
            }
            ebs[i] = s;
        }
        return;
    }
    __shared__ float sw[12288];
    for (int i = t * 4; i < 12288; i += 1024)
        *(float4*)(sw + i) = *(const float4*)(qw + i);
    __syncthreads();
    const int lane = t & 63, g = t >> 6;
    const int p = blockIdx.x * 64 + lane;
    const int b = p >> 12, hw = p & 4095;
    const float* xp = x + b * 262144 + hw;
    float xr[64];
    float s = 0.f;
#pragma unroll
    for (int c = 0; c < 64; ++c) { float v = xp[c * 4096]; xr[c] = v; s += v; }
    float m = s * 0.015625f;
    float s2 = 0.f;
#pragma unroll
    for (int c = 0; c < 64; ++c) { float d = xr[c] - m; s2 += d * d; }
    float rstd = rsqrtf(s2 * 0.015625f + 1e-5f);
#pragma unroll
    for (int c = 0; c < 64; ++c) xr[c] = (xr[c] - m) * rstd * n1w[c] + n1b[c];
    float* orow = qkv_all + (size_t)p * 192;
    for (int i = 0; i < 48; ++i) {
        int o = g * 48 + i;
        const float* wr = sw + o * 64;
        float acc = qb[o];
#pragma unroll
        for (int c = 0; c < 64; ++c) acc += xr[c] * wr[c];
        orow[o] = acc;
    }
}

// ---------------- K2: attention + neighbor-x sum -> out_sumed^T ----------------
// block = 32 pixels (one half image-row) x 8 heads = 256 threads
__global__ __launch_bounds__(256) void k_attn(
    const float* __restrict__ x, const float* __restrict__ qkv_all,
    const float* __restrict__ qkvc, const float* __restrict__ eb, const float* __restrict__ ebs,
    float* __restrict__ osT)
{
    __shared__ float sq[108 * 194];  // qkv rows, stride 194 (bank stride 2, b64-aligned)
    __shared__ float sx[108 * 66];   // raw x rows [rowcol][c], stride 66
    __shared__ float seb[2400];
    __shared__ float sebs[200];
    __shared__ float sqc[192];
    const int t = threadIdx.x;
    const int p0 = blockIdx.x * 32;
    const int b = p0 >> 12;
    const int hw0 = p0 & 4095;
    const int hrow = hw0 >> 6, w0 = hw0 & 63;

    for (int i = t; i < 192; i += 256) sqc[i] = qkvc[i];
    for (int i = t; i < 2400; i += 256) seb[i] = eb[i];
    for (int i = t; i < 200; i += 256) sebs[i] = ebs[i];
    // stage qkv rows: rr in 0..2 (img rows hrow-2..hrow), cc in 0..35 (cols w0-2..w0+33)
    for (int idx = t; idx < 108 * 96; idx += 256) {
        int row = idx / 96, o2 = (idx - row * 96) * 2;
        int rr = row / 36, cc = row - rr * 36;
        int gr = hrow - 2 + rr, gc = w0 - 2 + cc;
        float2 v;
        if (gr >= 0 && gc >= 0 && gc < 64)
            v = *(const float2*)(qkv_all + (size_t)((b << 12) + (gr << 6) + gc) * 192 + o2);
        else
            v = make_float2(qkvc[o2], qkvc[o2 + 1]);
        *(float2*)(sq + row * 194 + o2) = v;
    }
    // stage raw x for the same 108 positions
    for (int idx = t; idx < 6912; idx += 256) {
        int r = idx / 2304, rem = idx - r * 2304, c = rem / 36, ww = rem - c * 36;
        int gr = hrow - 2 + r, gc = w0 - 2 + ww;
        float v = (gr >= 0 && gc >= 0 && gc < 64) ? x[b * 262144 + c * 4096 + (gr << 6) + gc] : 0.f;
        sx[(r * 36 + ww) * 66 + c] = v;
    }
    __syncthreads();

    const int pix = t & 31, h = t >> 5, hb = h * 8;

    // neighbor x sum over the 12 unmasked slots
    float xs[8];
#pragma unroll
    for (int d = 0; d < 8; ++d) xs[d] = 0.f;
#pragma unroll
    for (int s = 0; s < 12; ++s) {
        const float* xr = sx + ((s / 5) * 36 + pix + (s % 5)) * 66 + hb;
#pragma unroll
        for (int d = 0; d < 8; ++d) xs[d] += xr[d];
    }
    // constant-q dot row: edc[k] = exp(q_c . k_k), ecc = exp(q_c . k_c)
    float qch[8];
#pragma unroll
    for (int d = 0; d < 8; ++d) qch[d] = sqc[hb + d] * SC;
    float edc[12], ecc;
#pragma unroll
    for (int k = 0; k < 13; ++k) {
        const float* kp = (k < 12) ? (sq + ((k / 5) * 36 + pix + (k % 5)) * 194 + 64 + hb)
                                   : (sqc + 64 + hb);
        float dd = 0.f;
#pragma unroll
        for (int d = 0; d < 8; ++d) dd += qch[d] * kp[d];
        if (k < 12) edc[k] = __expf(dd); else ecc = __expf(dd);
    }
    float w[12], wc = 0.f;
#pragma unroll
    for (int k = 0; k < 12; ++k) w[k] = 0.f;

    // real q rows (slots 0..11), chunks of 4 to amortize k-row LDS reads
#pragma unroll
    for (int qc = 0; qc < 3; ++qc) {
        float qr[4][8];
#pragma unroll
        for (int qq = 0; qq < 4; ++qq) {
            const int s = qc * 4 + qq;
            const float* qp = sq + ((s / 5) * 36 + pix + (s % 5)) * 194 + hb;
#pragma unroll
            for (int d = 0; d < 8; ++d) qr[qq][d] = qp[d] * SC;
        }
        float er[4][13];
#pragma unroll
        for (int k = 0; k < 13; ++k) {
            float kr[8];
            const float* kp = (k < 12) ? (sq + ((k / 5) * 36 + pix + (k % 5)) * 194 + 64 + hb)
                                       : (sqc + 64 + hb);
#pragma unroll
            for (int d = 0; d < 8; ++d) kr[d] = kp[d];
#pragma unroll
            for (int qq = 0; qq < 4; ++qq) {
                float dd = 0.f;
#pragma unroll
                for (int d = 0; d < 8; ++d) dd += qr[qq][d] * kr[d];
                er[qq][k] = dd;
            }
        }
#pragma unroll
        for (int qq = 0; qq < 4; ++qq) {
            const int s = qc * 4 + qq;
            const float* ebr = seb + (h * 25 + s) * 12;
            float ebsv = sebs[h * 25 + s];
            float ec = __expf(er[qq][12]);
            float tt[12];
            float rs = ec * ebsv;
#pragma unroll
            for (int k = 0; k < 12; ++k) { float e = __expf(er[qq][k]) * ebr[k]; tt[k] = e; rs += e; }
            float inv = frcp(rs);
#pragma unroll
            for (int k = 0; k < 12; ++k) w[k] += tt[k] * inv;
            wc += ec * ebsv * inv;
        }
    }
    // constant q rows (12..24): share edc/ecc, differ only in bias row
#pragma unroll
    for (int q = 12; q < 25; ++q) {
        const float* ebr = seb + (h * 25 + q) * 12;
        float ebsv = sebs[h * 25 + q];
        float rs = ecc * ebsv;
        float tt[12];
#pragma unroll
        for (int k = 0; k < 12; ++k) { float e = edc[k] * ebr[k]; tt[k] = e; rs += e; }
        float inv = frcp(rs);
#pragma unroll
        for (int k = 0; k < 12; ++k) w[k] += tt[k] * inv;
        wc += ecc * ebsv * inv;
    }
    // out = sum_k w[k] * v[k] + wc * v_const + xsum, write transposed [c][p]
    float out[8];
#pragma unroll
    for (int d = 0; d < 8; ++d) out[d] = wc * sqc[128 + hb + d];
#pragma unroll
    for (int k = 0; k < 12; ++k) {
        const float* vr = sq + ((k / 5) * 36 + pix + (k % 5)) * 194 + 128 + hb;
#pragma unroll
        for (int d = 0; d < 8; ++d) out[d] += w[k] * vr[d];
    }
    const int p = p0 + pix;
#pragma unroll
    for (int d = 0; d < 8; ++d) osT[(size_t)(hb + d) * 16384 + p] = out[d] + xs[d];
}

// ---------------- K3: LN2 + MLP(GELU) + residual + proj ----------------
// block = 64 pixels x 8 slices = 512 threads
__global__ __launch_bounds__(512) void k_mlp(
    const float* __restrict__ osT, const float* __restrict__ n2w, const float* __restrict__ n2b,
    const float* __restrict__ w1, const float* __restrict__ b1,
    const float* __restrict__ w2, const float* __restrict__ b2,
    const float* __restrict__ pw, const float* __restrict__ pb,
    float* __restrict__ out)
{
    __shared__ _Float16 sW1[16384];
    __shared__ _Float16 sW2[16384];
    __shared__ float sP[4096];
    __shared__ _Float16 sH[64 * 258];
    __shared__ float sY[64 * 66];
    __shared__ float sb1[256], sb2[64], spb[64];
    const int t = threadIdx.x;
    for (int i = t; i < 16384; i += 512) sW1[i] = (_Float16)w1[i];
    for (int i = t; i < 16384; i += 512) sW2[i] = (_Float16)w2[i];
    for (int i = t; i < 4096; i += 512) sP[i] = pw[i];
    if (t < 256) sb1[t] = b1[t];
    if (t < 64) { sb2[t] = b2[t]; spb[t] = pb[t]; }
    __syncthreads();
    const int pix = t & 63, sl = t >> 6;
    const int p = blockIdx.x * 64 + pix;
    float a[64];
    float s = 0.f;
#pragma unroll
    for (int c = 0; c < 64; ++c) { float v = osT[(size_t)c * 16384 + p]; a[c] = v; s += v; }
    float m = s * 0.015625f;
    float s2 = 0.f;
#pragma unroll
    for (int c = 0; c < 64; ++c) { float d = a[c] - m; s2 += d * d; }
    float rstd = rsqrtf(s2 * 0.015625f + 1e-5f);
    h2f av[32];
#pragma unroll
    for (int c = 0; c < 32; ++c) {
        float e0 = (a[2 * c] - m) * rstd * n2w[2 * c] + n2b[2 * c];
        float e1 = (a[2 * c + 1] - m) * rstd * n2w[2 * c + 1] + n2b[2 * c + 1];
        h2f v; v.x = (_Float16)e0; v.y = (_Float16)e1;
        av[c] = v;
    }
    // fc1 + exact GELU
    for (int i = 0; i < 32; ++i) {
        int j = sl * 32 + i;
        const h2f* wr = (const h2f*)(sW1 + j * 64);
        float acc = sb1[j];
#pragma unroll
        for (int cp = 0; cp < 32; ++cp) acc = fdot2f(av[cp], wr[cp], acc);
        float g = 0.5f * acc * (1.f + erff(acc * 0.70710678118654752f));
        sH[pix * 258 + j] = (_Float16)g;
    }
    __syncthreads();
    // fc2 + residual
#pragma unroll
    for (int mm = 0; mm < 8; ++mm) {
        int o = sl * 8 + mm;
        const h2f* wr = (const h2f*)(sW2 + o * 256);
        const h2f* hr = (const h2f*)(sH + pix * 258);
        float acc = sb2[o];
#pragma unroll 32
        for (int jp = 0; jp < 128; ++jp) acc = fdot2f(hr[jp], wr[jp], acc);
        float resid = osT[(size_t)o * 16384 + p];
        sY[pix * 66 + o] = acc + resid;
    }
    __syncthreads();
    const int bimg = p >> 12, hw = p & 4095, hh = hw >> 6, ww = hw & 63;
#pragma unroll
    for (int mm = 0; mm < 8; ++mm) {
        int o = sl * 8 + mm;
        const float* wr = sP + o * 64;
        const float* yr = sY + pix * 66;
        float acc = spb[o];
#pragma unroll
        for (int c = 0; c < 64; ++c) acc += yr[c] * wr[c];
        out[(size_t)(((bimg * 64 + o) * 64 + hh) * 64) + ww] = acc;
    }
}

extern "C" void kernel_launch(void* const* d_in, const int* in_sizes, int n_in,
                              void* d_out, int out_size, void* d_ws, size_t ws_size,
                              hipStream_t stream) {
    const float* x   = (const float*)d_in[0];
    const float* n1w = (const float*)d_in[1];
    const float* n1b = (const float*)d_in[2];
    const float* qw  = (const float*)d_in[3];
    const float* qb  = (const float*)d_in[4];
    const float* rpb = (const float*)d_in[5];
    const float* n2w = (const float*)d_in[6];
    const float* n2b = (const float*)d_in[7];
    const float* w1  = (const float*)d_in[8];
    const float* b1  = (const float*)d_in[9];
    const float* w2  = (const float*)d_in[10];
    const float* b2  = (const float*)d_in[11];
    const float* pw  = (const float*)d_in[12];
    const float* pb  = (const float*)d_in[13];
    float* out = (float*)d_out;

    float* ws = (float*)d_ws;
    float* qkv_all = ws;                        // 16384*192
    float* osT     = qkv_all + 16384 * 192;     // 64*16384 (transposed out_sumed)
    float* qkvc    = osT + 64 * 16384;          // 192
    float* eb      = qkvc + 192;                // 2400
    float* ebs     = eb + 2400;                 // 200   (total ~16.8 MB)

    hipLaunchKernelGGL(k_qkv, dim3(257), dim3(256), 0, stream,
                       x, n1w, n1b, qw, qb, rpb, qkv_all, qkvc, eb, ebs);
    hipLaunchKernelGGL(k_attn, dim3(512), dim3(256), 0, stream,
                       x, qkv_all, qkvc, eb, ebs, osT);
    hipLaunchKernelGGL(k_mlp, dim3(256), dim3(512), 0, stream,
                       osT, n2w, n2b, w1, b1, w2, b2, pw, pb, out);
}

// Round 4
// 190.343 us; speedup vs baseline: 1.1770x; 1.1770x over previous
//
#include <hip/hip_runtime.h>
#include <hip/hip_bf16.h>

// CausalAttentionModule: B=4, C=64, H=W=64, NH=8, hd=8, BL=5, BS=25, MASK_ONES=12
// Algebra: unfold rows = neighbor-pixel gathers -> LN1+QKV once per pixel;
// masked/OOB rows -> constant qkv row; sum over q of attn@v -> column sums w[k];
// k>=12 tail collapses to scalar w[12]; exp(dot+bias)=exp(dot)*exp(bias) precomputed.
// Round 4: occupancy-first restructure (all kernels were 4-8 waves/CU, latency-bound).

typedef _Float16 h2f __attribute__((ext_vector_type(2)));
typedef _Float16 h8  __attribute__((ext_vector_type(8)));
union u8h { h8 v; h2f p[4]; };

__device__ __forceinline__ float fdot2f(h2f a, h2f b, float c) {
#if defined(__has_builtin)
#if __has_builtin(__builtin_amdgcn_fdot2)
    return __builtin_amdgcn_fdot2(a, b, c, false);
#else
    return c + (float)a.x*(float)b.x + (float)a.y*(float)b.y;
#endif
#else
    return c + (float)a.x*(float)b.x + (float)a.y*(float)b.y;
#endif
}
__device__ __forceinline__ float dot8(u8h a, u8h b) {
    float c = 0.f;
    c = fdot2f(a.p[0], b.p[0], c);
    c = fdot2f(a.p[1], b.p[1], c);
    c = fdot2f(a.p[2], b.p[2], c);
    c = fdot2f(a.p[3], b.p[3], c);
    return c;
}
__device__ __forceinline__ float frcp(float x) {
#if defined(__has_builtin)
#if __has_builtin(__builtin_amdgcn_rcpf)
    return __builtin_amdgcn_rcpf(x);
#else
    return 1.0f/x;
#endif
#else
    return 1.0f/x;
#endif
}

#define SC 0.35355339059327373f  // 1/sqrt(8)

// ---------------- K1: LN1+QKV (512 blk) + xsum (256 blk) + setup (1 blk) ----------------
__global__ __launch_bounds__(256, 4) void k_qkv(
    const float* __restrict__ x, const float* __restrict__ n1w, const float* __restrict__ n1b,
    const float* __restrict__ qw, const float* __restrict__ qb, const float* __restrict__ rpb,
    const float* __restrict__ w1, const float* __restrict__ w2, const float* __restrict__ pw,
    _Float16* __restrict__ qkv, _Float16* __restrict__ qkvc_h,
    _Float16* __restrict__ ebh, float* __restrict__ ebs,
    _Float16* __restrict__ w1h, _Float16* __restrict__ w2h, _Float16* __restrict__ pwh,
    float* __restrict__ osT)
{
    const int t = threadIdx.x;
    const int bid = blockIdx.x;
    if (bid >= 512) {
        if (bid == 768) {
            // qkv_const = LN(0) @ qkv_w^T + qkv_b = n1b @ qkv_w^T + qkv_b
            if (t < 192) {
                float acc = qb[t];
                for (int c = 0; c < 64; ++c) acc += n1b[c]*qw[t*64 + c];
                qkvc_h[t] = (_Float16)acc;
            }
            // exp(bias) table for k<12: ebh[h][q][k]
            for (int i = t; i < 2400; i += 256) {
                int h = i/300, r = i%300, q = r/12, k = r%12;
                int idx = (q/5 - k/5 + 4)*9 + (q%5 - k%5 + 4);
                ebh[i] = (_Float16)__expf(rpb[idx*8 + h]);
            }
            // row sums over k=12..24
            for (int i = t; i < 200; i += 256) {
                int h = i/25, q = i%25; float s = 0.f;
                for (int k = 12; k < 25; ++k) {
                    int idx = (q/5 - k/5 + 4)*9 + (q%5 - k%5 + 4);
                    s += __expf(rpb[idx*8 + h]);
                }
                ebs[i] = s;
            }
            // f16 weight copies for K3
            for (int i = t; i < 16384; i += 256) w1h[i] = (_Float16)w1[i];
            for (int i = t; i < 16384; i += 256) w2h[i] = (_Float16)w2[i];
            for (int i = t; i < 4096;  i += 256) pwh[i] = (_Float16)pw[i];
            return;
        }
        // xsum: osT[c][p] = sum of the 12 unmasked neighbors' x (zero-padded)
        for (int i = 0; i < 16; ++i) {
            int idx = (bid - 512)*4096 + i*256 + t;
            int c = idx >> 14, p = idx & 16383, b = p >> 12, hw = p & 4095;
            int hh = hw >> 6, ww = hw & 63;
            const float* pl = x + b*262144 + c*4096;
            float s = 0.f;
            #pragma unroll
            for (int dr = -2; dr <= 0; ++dr) {
                int r = hh + dr; if (r < 0) continue;
                int cmax = (dr == 0) ? -1 : 2;
                #pragma unroll
                for (int dc = -2; dc <= 2; ++dc) {
                    if (dc > cmax) break;
                    int w2c = ww + dc;
                    if (w2c >= 0 && w2c < 64) s += pl[(r << 6) + w2c];
                }
            }
            osT[(size_t)c*16384 + p] = s;
        }
        return;
    }
    // main: 32 pixels, 8 groups x 24 outputs
    __shared__ alignas(16) h2f sw[6144];           // qkv_w as f16  (24 KB)
    __shared__ float sX[2080];                      // 32 x 65
    __shared__ alignas(16) _Float16 sOut[6400];     // 32 x 200
    for (int i = t; i < 6144; i += 256) {
        float2 v = *(const float2*)(qw + i*2);
        sw[i] = h2f{(_Float16)v.x, (_Float16)v.y};
    }
    const int p0 = bid*32;
    const int b = p0 >> 12, hw0 = p0 & 4095;
    for (int i = t; i < 2048; i += 256) {
        int c = i >> 5, pp = i & 31;
        sX[pp*65 + c] = x[b*262144 + c*4096 + hw0 + pp];
    }
    __syncthreads();
    const int pix = t & 31, g = t >> 5;
    float s = 0.f, s2 = 0.f;
    #pragma unroll
    for (int c = 0; c < 64; ++c) { float v = sX[pix*65 + c]; s += v; s2 += v*v; }
    float m = s*0.015625f;
    float rstd = rsqrtf(fmaxf(s2*0.015625f - m*m, 0.f) + 1e-5f);
    h2f av[32];
    #pragma unroll
    for (int c = 0; c < 32; ++c) {
        float e0 = (sX[pix*65 + 2*c]     - m)*rstd*n1w[2*c]     + n1b[2*c];
        float e1 = (sX[pix*65 + 2*c + 1] - m)*rstd*n1w[2*c + 1] + n1b[2*c + 1];
        av[c] = h2f{(_Float16)e0, (_Float16)e1};
    }
    for (int i = 0; i < 24; ++i) {
        int o = g*24 + i;
        const h2f* wr = sw + o*32;
        float acc = qb[o];
        #pragma unroll
        for (int cp = 0; cp < 32; ++cp) acc = fdot2f(av[cp], wr[cp], acc);
        sOut[pix*200 + o] = (_Float16)acc;
    }
    __syncthreads();
    // coalesced f16 store: rows of 192 f16 = 24 float4, contiguous across pixels
    for (int i = t; i < 768; i += 256) {
        int pp = i/24, d4 = i%24;
        ((float4*)qkv)[(size_t)p0*24 + i] = *(const float4*)(sOut + pp*200 + d4*8);
    }
}

// ---------------- K2: attention, q-split halves, osT += attn ----------------
// block = 512: pix(32) x head(8) x half(2). A: q 0..8; B: q 9..11 + 13 const-q rows.
__global__ __launch_bounds__(512, 4) void k_attn(
    const _Float16* __restrict__ qkv, const _Float16* __restrict__ qkvc_h,
    const _Float16* __restrict__ ebh, const float* __restrict__ ebs,
    float* __restrict__ osT)
{
    __shared__ alignas(16) _Float16 sq[21600];   // 108 rows x 200 f16 (43.2 KB)
    __shared__ _Float16 seb[2400];
    __shared__ float sebs[200];
    __shared__ alignas(16) _Float16 sqc[192];
    __shared__ float red[6656];                   // 256 x 2 x 13
    const int t = threadIdx.x;
    const int p0 = blockIdx.x*32;
    const int b = p0 >> 12, hw0 = p0 & 4095, hrow = hw0 >> 6, w0 = hw0 & 63;

    for (int i = t; i < 1200; i += 512) ((float*)seb)[i] = ((const float*)ebh)[i];
    for (int i = t; i < 200; i += 512) sebs[i] = ebs[i];
    if (t < 96) ((float*)sqc)[t] = ((const float*)qkvc_h)[t];
    // stage qkv window: rows (hrow-2..hrow) x cols (w0-2..w0+33), OOB -> const row
    for (int i = t; i < 2592; i += 512) {
        int row = i/24, d4 = i%24;
        int rr = row/36, cc = row%36;
        int gr = hrow - 2 + rr, gc = w0 - 2 + cc;
        float4 v;
        if (gr >= 0 && gc >= 0 && gc < 64)
            v = ((const float4*)qkv)[(size_t)((b << 12) + (gr << 6) + gc)*24 + d4];
        else
            v = ((const float4*)qkvc_h)[d4];
        *(float4*)(sq + row*200 + d4*8) = v;
    }
    __syncthreads();

    const int pix = t & 31, h = (t >> 5) & 7, half = t >> 8, hb = h*8;
    // hoist the 12 K-fragments into registers (reused by every q-row)
    u8h kreg[12];
    #pragma unroll
    for (int k = 0; k < 12; ++k) {
        int rw = (k/5)*36 + pix + (k%5);
        kreg[k].v = *(const h8*)(sq + rw*200 + 64 + hb);
    }
    u8h kc; kc.v = *(const h8*)(sqc + 64 + hb);

    float w[13];
    #pragma unroll
    for (int k = 0; k < 13; ++k) w[k] = 0.f;

    const int qlo = half ? 9 : 0, qhi = half ? 12 : 9;
    for (int sIdx = qlo; sIdx < qhi; ++sIdx) {
        int rw = (sIdx/5)*36 + pix + (sIdx%5);
        u8h qu; qu.v = *(const h8*)(sq + rw*200 + hb);
        const _Float16* ebr = seb + (h*25 + sIdx)*12;
        float rs = __expf(dot8(qu, kc)*SC) * sebs[h*25 + sIdx];
        float wcq = rs;
        float tt[12];
        #pragma unroll
        for (int k = 0; k < 12; ++k) {
            float e = __expf(dot8(qu, kreg[k])*SC) * (float)ebr[k];
            tt[k] = e; rs += e;
        }
        float inv = frcp(rs);
        #pragma unroll
        for (int k = 0; k < 12; ++k) w[k] += tt[k]*inv;
        w[12] += wcq*inv;
    }
    if (half) {
        u8h qcu; qcu.v = *(const h8*)(sqc + hb);
        float edc[12];
        #pragma unroll
        for (int k = 0; k < 12; ++k) edc[k] = __expf(dot8(qcu, kreg[k])*SC);
        float ecc = __expf(dot8(qcu, kc)*SC);
        for (int q = 12; q < 25; ++q) {
            const _Float16* ebr = seb + (h*25 + q)*12;
            float rs = ecc * sebs[h*25 + q];
            float wcq = rs;
            float tt[12];
            #pragma unroll
            for (int k = 0; k < 12; ++k) { float e = edc[k]*(float)ebr[k]; tt[k] = e; rs += e; }
            float inv = frcp(rs);
            #pragma unroll
            for (int k = 0; k < 12; ++k) w[k] += tt[k]*inv;
            w[12] += wcq*inv;
        }
    }
    // combine the two halves' partial column sums
    const int ph = (h << 5) + pix;
    {
        float* my = red + (ph*2 + half)*13;
        #pragma unroll
        for (int k = 0; k < 13; ++k) my[k] = w[k];
    }
    __syncthreads();
    {
        const float* ot = red + (ph*2 + (half ^ 1))*13;
        #pragma unroll
        for (int k = 0; k < 13; ++k) w[k] += ot[k];
    }
    // PV: each half writes 4 of the 8 dims; osT already holds xsum -> accumulate
    const int d0 = half*4;
    float out0, out1, out2, out3;
    {
        const h2f* vcp = (const h2f*)(sqc + 128 + hb + d0);
        h2f v0 = vcp[0], v1 = vcp[1];
        out0 = w[12]*(float)v0.x; out1 = w[12]*(float)v0.y;
        out2 = w[12]*(float)v1.x; out3 = w[12]*(float)v1.y;
    }
    #pragma unroll
    for (int k = 0; k < 12; ++k) {
        int rw = (k/5)*36 + pix + (k%5);
        const h2f* vp = (const h2f*)(sq + rw*200 + 128 + hb + d0);
        h2f v0 = vp[0], v1 = vp[1];
        float wk = w[k];
        out0 += wk*(float)v0.x; out1 += wk*(float)v0.y;
        out2 += wk*(float)v1.x; out3 += wk*(float)v1.y;
    }
    const int p = p0 + pix;
    float* op = osT + (size_t)(hb + d0)*16384 + p;
    op[0]       += out0;
    op[16384]   += out1;
    op[32768]   += out2;
    op[49152]   += out3;
}

// ---------------- K3: LN2 + MLP(GELU) + residual + proj ----------------
// block = 512: pix(32) x slice(16). Weights read f16 from global (wave-uniform rows).
__global__ __launch_bounds__(512, 4) void k_mlp(
    const float* __restrict__ osT, const float* __restrict__ n2w, const float* __restrict__ n2b,
    const float* __restrict__ b1, const float* __restrict__ b2, const float* __restrict__ pb,
    const _Float16* __restrict__ w1h, const _Float16* __restrict__ w2h, const _Float16* __restrict__ pwh,
    float* __restrict__ out)
{
    __shared__ float sA[2112];                    // 32 x 66
    __shared__ h2f sAv[1088];                     // 32 x 34
    __shared__ alignas(16) _Float16 sH[8448];     // 32 x 264
    __shared__ alignas(16) _Float16 sY[2304];     // 32 x 72
    __shared__ float sb1[256], sb2[64], spb[64], sM[32], sR[32], sN[128];
    const int t = threadIdx.x;
    const int p0 = blockIdx.x*32;
    for (int i = t; i < 2048; i += 512) {
        int c = i >> 5, pp = i & 31;
        sA[pp*66 + c] = osT[(size_t)c*16384 + p0 + pp];
    }
    if (t < 256) sb1[t] = b1[t];
    else if (t < 320) sb2[t - 256] = b2[t - 256];
    else if (t < 384) spb[t - 320] = pb[t - 320];
    else if (t < 448) sN[t - 384] = n2w[t - 384];
    else sN[64 + (t - 448)] = n2b[t - 448];
    __syncthreads();
    if (t < 32) {
        float s = 0.f, s2 = 0.f;
        for (int c = 0; c < 64; ++c) { float v = sA[t*66 + c]; s += v; s2 += v*v; }
        float m = s*0.015625f;
        sM[t] = m; sR[t] = rsqrtf(fmaxf(s2*0.015625f - m*m, 0.f) + 1e-5f);
    }
    __syncthreads();
    for (int i = t; i < 1024; i += 512) {
        int pp = i >> 5, pr = i & 31;
        float m = sM[pp], r = sR[pp];
        float e0 = (sA[pp*66 + 2*pr]     - m)*r*sN[2*pr]     + sN[64 + 2*pr];
        float e1 = (sA[pp*66 + 2*pr + 1] - m)*r*sN[2*pr + 1] + sN[64 + 2*pr + 1];
        sAv[pp*34 + pr] = h2f{(_Float16)e0, (_Float16)e1};
    }
    __syncthreads();
    const int pix = t & 31, sl = t >> 5;
    const int p = p0 + pix;
    const h2f* avr = sAv + pix*34;
    // fc1 + exact GELU
    for (int i = 0; i < 16; ++i) {
        int j = sl*16 + i;
        const h2f* wr = (const h2f*)(w1h + j*64);
        float acc = sb1[j];
        #pragma unroll
        for (int cp = 0; cp < 32; ++cp) acc = fdot2f(avr[cp], wr[cp], acc);
        float g = 0.5f*acc*(1.f + erff(acc*0.70710678118654752f));
        sH[pix*264 + j] = (_Float16)g;
    }
    __syncthreads();
    // fc2 + residual
    const h2f* hr = (const h2f*)(sH + pix*264);
    for (int mm = 0; mm < 4; ++mm) {
        int o = sl*4 + mm;
        const h2f* wr = (const h2f*)(w2h + o*256);
        float acc = sb2[o];
        #pragma unroll 32
        for (int jp = 0; jp < 128; ++jp) acc = fdot2f(hr[jp], wr[jp], acc);
        float y = acc + osT[(size_t)o*16384 + p];
        sY[pix*72 + o] = (_Float16)y;
    }
    __syncthreads();
    const int bimg = p >> 12, hw = p & 4095, hh = hw >> 6, ww = hw & 63;
    const h2f* yr = (const h2f*)(sY + pix*72);
    for (int mm = 0; mm < 4; ++mm) {
        int o = sl*4 + mm;
        const h2f* wr = (const h2f*)(pwh + o*64);
        float acc = spb[o];
        #pragma unroll
        for (int c = 0; c < 32; ++c) acc = fdot2f(yr[c], wr[c], acc);
        out[(size_t)(((bimg*64 + o)*64 + hh)*64) + ww] = acc;
    }
}

extern "C" void kernel_launch(void* const* d_in, const int* in_sizes, int n_in,
                              void* d_out, int out_size, void* d_ws, size_t ws_size,
                              hipStream_t stream) {
    const float* x   = (const float*)d_in[0];
    const float* n1w = (const float*)d_in[1];
    const float* n1b = (const float*)d_in[2];
    const float* qw  = (const float*)d_in[3];
    const float* qb  = (const float*)d_in[4];
    const float* rpb = (const float*)d_in[5];
    const float* n2w = (const float*)d_in[6];
    const float* n2b = (const float*)d_in[7];
    const float* w1  = (const float*)d_in[8];
    const float* b1  = (const float*)d_in[9];
    const float* w2  = (const float*)d_in[10];
    const float* b2  = (const float*)d_in[11];
    const float* pw  = (const float*)d_in[12];
    const float* pb  = (const float*)d_in[13];
    float* out = (float*)d_out;

    float* ws = (float*)d_ws;
    _Float16* qkv    = (_Float16*)ws;              // 16384*192 f16 = 1,572,864 floats
    float*    osT    = ws + 1572864;               // 64*16384 f32
    _Float16* qkvc_h = (_Float16*)(ws + 2621440);  // 192 f16 (96 floats)
    _Float16* ebh    = (_Float16*)(ws + 2621536);  // 2400 f16 (1200)
    float*    ebsp   = ws + 2622736;               // 200 f32
    _Float16* w1h    = (_Float16*)(ws + 2622936);  // 16384 f16 (8192)
    _Float16* w2h    = (_Float16*)(ws + 2631128);  // 16384 f16 (8192)
    _Float16* pwh    = (_Float16*)(ws + 2639320);  // 4096 f16 (2048)  -> total ~10.6 MB

    hipLaunchKernelGGL(k_qkv, dim3(769), dim3(256), 0, stream,
                       x, n1w, n1b, qw, qb, rpb, w1, w2, pw,
                       qkv, qkvc_h, ebh, ebsp, w1h, w2h, pwh, osT);
    hipLaunchKernelGGL(k_attn, dim3(512), dim3(512), 0, stream,
                       qkv, qkvc_h, ebh, ebsp, osT);
    hipLaunchKernelGGL(k_mlp, dim3(512), dim3(512), 0, stream,
                       osT, n2w, n2b, b1, b2, pb, w1h, w2h, pwh, out);
}